// Round 9
// baseline (42.993 us; speedup 1.0000x reference)
//
#include <hip/hip_runtime.h>
#include <hip/hip_bf16.h>

#define B_  256
#define T_  256
#define C_  384
#define HS_ 64
#define BT_ (B_*T_)

typedef __attribute__((ext_vector_type(8))) short short8;
typedef __attribute__((ext_vector_type(4))) float f32x4;

// ---------- helpers ----------
__device__ __forceinline__ unsigned short f2bf(float f) {
    unsigned u = __float_as_uint(f);
    u += 0x7FFFu + ((u >> 16) & 1u);   // round-to-nearest-even
    return (unsigned short)(u >> 16);
}

// ---------- kernel 0: W -> MFMA-fragment-ordered bf16 ----------
// Wfrag[s][wn][f][lane] (short8): element col n = wn*48+f*16+(lane&15),
// k = s*32+(lane>>4)*8+j.  Q columns pre-scaled by 384^-0.5.
__global__ __launch_bounds__(256) void prep_wfrag(
    const float* __restrict__ Wq, const float* __restrict__ Wk,
    const float* __restrict__ Wv, unsigned short* __restrict__ Wfrag)
{
    const int tid  = blockIdx.x * 256 + threadIdx.x;   // 9216 threads
    const int lane = tid & 63;
    const int q    = tid >> 6;
    const int f    = q % 3;
    const int q2   = q / 3;
    const int wn   = q2 & 3;
    const int s    = q2 >> 2;

    const int n     = wn * 48 + f * 16 + (lane & 15);
    const int kbase = s * 32 + (lane >> 4) * 8;
    const float* src = (n < 64) ? Wq : (n < 128) ? Wk : Wv;
    const int c      = n & 63;
    const float scale = (n < 64) ? 0.05103103630798288f : 1.0f;

    short8 out;
    #pragma unroll
    for (int j = 0; j < 8; ++j)
        out[j] = (short)f2bf(src[(size_t)(kbase + j) * HS_ + c] * scale);
    *(short8*)&Wfrag[(size_t)tid * 8] = out;
}

// ---------- kernel 1: QKV GEMM, 1024 blocks x 4 waves (4 blocks/CU) ----------
// Tile M=64 x N=192, K-step 32, depth-2 X pipeline, W from L2 (frag-ordered).
// Epilogue writes Q,K (natural [tok][64]) and Vt ([b*64+h][tok]) to GLOBAL.
__global__ __launch_bounds__(256, 4) void qkv_a(
    const float* __restrict__ X, const unsigned short* __restrict__ Wfrag,
    unsigned short* __restrict__ Qg, unsigned short* __restrict__ Kg,
    unsigned short* __restrict__ Vtg)
{
    __shared__ unsigned short Xs[2][64 * 40];   // 10240 B
    const int t    = threadIdx.x;
    const int w    = t >> 6;        // 0..3 = wn (all waves share the 64 rows)
    const int lane = t & 63;
    const int lo   = lane & 15;
    const int hi   = lane >> 4;
    const int row0 = blockIdx.x * 64;

    const float* Xb = X + (size_t)row0 * C_;
    const short8* Wf = (const short8*)Wfrag;

    const int srow  = t >> 2;       // 0..63
    const int squad = t & 3;        // 8-float chunk of the 32-k slice

    auto stage_load = [&](int k0, float4* g) {
        const float* p = Xb + (size_t)srow * C_ + k0 + squad * 8;
        g[0] = *(const float4*)(p);
        g[1] = *(const float4*)(p + 4);
    };
    auto stage_write = [&](int buf, const float4* g) {
        short8 p;
        p[0] = (short)f2bf(g[0].x); p[1] = (short)f2bf(g[0].y);
        p[2] = (short)f2bf(g[0].z); p[3] = (short)f2bf(g[0].w);
        p[4] = (short)f2bf(g[1].x); p[5] = (short)f2bf(g[1].y);
        p[6] = (short)f2bf(g[1].z); p[7] = (short)f2bf(g[1].w);
        *(short8*)&Xs[buf][srow * 40 + squad * 8] = p;
    };
    auto load_w = [&](int s, short8* wf) {      // coalesced fragment loads
        const short8* base = Wf + ((size_t)(s * 4 + w) * 3) * 64 + lane;
        #pragma unroll
        for (int f = 0; f < 3; ++f)
            wf[f] = base[f * 64];
    };

    float4 gx[2][2];
    short8 wfr[2][3];
    stage_load(0, gx[0]);
    load_w(0, wfr[0]);
    stage_load(32, gx[1]);
    stage_write(0, gx[0]);
    __syncthreads();

    f32x4 acc[4][3];
    #pragma unroll
    for (int m = 0; m < 4; ++m)
        #pragma unroll
        for (int f = 0; f < 3; ++f)
            acc[m][f] = (f32x4){0.f, 0.f, 0.f, 0.f};

    #pragma unroll 2
    for (int s = 0; s < 12; ++s) {
        const int cur = s & 1;
        if (s < 10) stage_load((s + 2) * 32, gx[cur]);
        if (s < 11) load_w(s + 1, wfr[cur ^ 1]);
        if (s < 11) stage_write(cur ^ 1, gx[cur ^ 1]);

        short8 af[4];                           // A-frag: row=lo, k=hi*8+j
        #pragma unroll
        for (int m = 0; m < 4; ++m)
            af[m] = *(const short8*)&Xs[cur][(m * 16 + lo) * 40 + hi * 8];
        #pragma unroll
        for (int m = 0; m < 4; ++m)
            #pragma unroll
            for (int f = 0; f < 3; ++f)
                acc[m][f] = __builtin_amdgcn_mfma_f32_16x16x32_bf16(af[m], wfr[cur][f], acc[m][f], 0, 0, 0);
        __syncthreads();
    }

    // epilogue -> global: D col = w*48+f*16+lo, row = row0+m*16+hi*4+r
    #pragma unroll
    for (int m = 0; m < 4; ++m) {
        const int grow = row0 + m * 16 + hi * 4;
        #pragma unroll
        for (int f = 0; f < 3; ++f) {
            const int base = w * 48 + f * 16;   // uniform per wave/frag
            const int n    = base + lo;
            if (base < 64) {
                #pragma unroll
                for (int r = 0; r < 4; ++r)
                    Qg[(size_t)(grow + r) * HS_ + n] = f2bf(acc[m][f][r]);
            } else if (base < 128) {
                #pragma unroll
                for (int r = 0; r < 4; ++r)
                    Kg[(size_t)(grow + r) * HS_ + (n - 64)] = f2bf(acc[m][f][r]);
            } else {
                ushort4 pk = { f2bf(acc[m][f][0]), f2bf(acc[m][f][1]),
                               f2bf(acc[m][f][2]), f2bf(acc[m][f][3]) };
                *(ushort4*)&Vtg[((size_t)(grow >> 8) * 64 + (n - 128)) * 256 + (grow & 255)] = pk;
            }
        }
    }
}

// ---------- kernel 2: causal flash attention (swapped MFMA), 1 block/batch ----------
// 1024 thr = 16 waves; K/Vt staged once (1 barrier), then barrier-free kv loop.
// LDS (u16): Ks[256][72] @0 (18432) | Vts[64][264] @18432 (16896) | P[16][640] @35328
#define BK_OFF 0
#define BV_OFF 18432
#define BP_OFF 35328
#define LDSP   40

__global__ __launch_bounds__(1024, 4) void attn_b(
    const unsigned short* __restrict__ Qg,
    const unsigned short* __restrict__ Kg,
    const unsigned short* __restrict__ Vtg,
    float* __restrict__ out)
{
    __shared__ unsigned short lds[45568];       // 91136 B
    const int t    = threadIdx.x;
    const int w    = t >> 6;
    const int lane = t & 63;
    const int lo   = lane & 15;
    const int hi   = lane >> 4;
    const int b    = blockIdx.x;

    // stage K and Vt (coalesced b128)
    {
        const uint4* gk = (const uint4*)(Kg + (size_t)b * 256 * HS_);
        #pragma unroll
        for (int i = 0; i < 2; ++i) {
            int idx = t + i * 1024;             // 2048 uint4 = 256 rows x 8
            int r = idx >> 3, c8 = (idx & 7) * 8;
            *(uint4*)&lds[BK_OFF + r * 72 + c8] = gk[idx];
        }
        const uint4* gv = (const uint4*)(Vtg + (size_t)b * 64 * 256);
        #pragma unroll
        for (int i = 0; i < 2; ++i) {
            int idx = t + i * 1024;             // 2048 uint4 = 64 rows x 32
            int r = idx >> 5, c8 = (idx & 31) * 8;
            *(uint4*)&lds[BV_OFF + r * 264 + c8] = gv[idx];
        }
    }
    __syncthreads();

    unsigned short* Pw = &lds[BP_OFF + w * 640];

    // SIMD-balanced tile assignment: SIMD g gets {g, 15-g, 4+g, 11-g} = 18 steps
    const int sg  = w & 3, pos = w >> 2;
    const int tq  = (pos == 0) ? sg : (pos == 1) ? 15 - sg : (pos == 2) ? 4 + sg : 11 - sg;

    {
        const int q_lane = tq * 16 + lo;
        const unsigned short* qp = Qg + ((size_t)(b * 256 + q_lane)) * HS_ + hi * 8;
        short8 qf0 = *(const short8*)qp;
        short8 qf1 = *(const short8*)(qp + 32);

        f32x4 acc_o[4];                         // O^T: acc_o[n][r] = O[h=n*16+hi*4+r][q=lo]
        #pragma unroll
        for (int n = 0; n < 4; ++n) acc_o[n] = (f32x4){0.f, 0.f, 0.f, 0.f};
        float Mr = -1e30f, Lr = 0.f;

        const int nsteps = (tq >> 1) + 1;
        for (int s = 0; s < nsteps; ++s) {
            const int kv0 = s * 32;
            f32x4 sb[2];
            sb[0] = (f32x4){0.f, 0.f, 0.f, 0.f};
            sb[1] = (f32x4){0.f, 0.f, 0.f, 0.f};
            __builtin_amdgcn_s_setprio(1);
            #pragma unroll
            for (int n = 0; n < 2; ++n) {
                const unsigned short* kb = &lds[BK_OFF + (kv0 + n * 16 + lo) * 72 + hi * 8];
                short8 kf0 = *(const short8*)kb;
                short8 kf1 = *(const short8*)(kb + 32);
                sb[n] = __builtin_amdgcn_mfma_f32_16x16x32_bf16(kf0, qf0, sb[n], 0, 0, 0);
                sb[n] = __builtin_amdgcn_mfma_f32_16x16x32_bf16(kf1, qf1, sb[n], 0, 0, 0);
            }
            __builtin_amdgcn_s_setprio(0);
            if (s == nsteps - 1) {              // causal: kv = kv0+n*16+hi*4+r
                #pragma unroll
                for (int n = 0; n < 2; ++n)
                    #pragma unroll
                    for (int r = 0; r < 4; ++r)
                        if (kv0 + n * 16 + hi * 4 + r > q_lane) sb[n][r] = -1e30f;
            }
            float pmax = fmaxf(fmaxf(fmaxf(sb[0][0], sb[0][1]), fmaxf(sb[0][2], sb[0][3])),
                               fmaxf(fmaxf(sb[1][0], sb[1][1]), fmaxf(sb[1][2], sb[1][3])));
            pmax = fmaxf(pmax, __shfl_xor(pmax, 16));
            pmax = fmaxf(pmax, __shfl_xor(pmax, 32));
            float Mn;
            if (__all(pmax - Mr <= 8.0f)) {     // T13 defer-max
                Mn = Mr;
            } else {
                Mn = fmaxf(Mr, pmax);
                const float fr = __expf(Mr - Mn);
                Mr = Mn;
                Lr *= fr;
                #pragma unroll
                for (int n = 0; n < 4; ++n) {
                    acc_o[n][0] *= fr; acc_o[n][1] *= fr;
                    acc_o[n][2] *= fr; acc_o[n][3] *= fr;
                }
            }
            float p0 = __expf(sb[0][0] - Mn), p1 = __expf(sb[0][1] - Mn);
            float p2 = __expf(sb[0][2] - Mn), p3 = __expf(sb[0][3] - Mn);
            float p4 = __expf(sb[1][0] - Mn), p5 = __expf(sb[1][1] - Mn);
            float p6 = __expf(sb[1][2] - Mn), p7 = __expf(sb[1][3] - Mn);
            float ls = ((p0 + p1) + (p2 + p3)) + ((p4 + p5) + (p6 + p7));
            ls += __shfl_xor(ls, 16);
            ls += __shfl_xor(ls, 32);
            Lr += ls;
            ushort4 w0 = { f2bf(p0), f2bf(p1), f2bf(p2), f2bf(p3) };
            ushort4 w1 = { f2bf(p4), f2bf(p5), f2bf(p6), f2bf(p7) };
            *(ushort4*)&Pw[lo * LDSP + hi * 4]      = w0;
            *(ushort4*)&Pw[lo * LDSP + 16 + hi * 4] = w1;
            short8 pf = *(const short8*)&Pw[lo * LDSP + hi * 8];
            __builtin_amdgcn_s_setprio(1);
            #pragma unroll
            for (int n = 0; n < 4; ++n) {
                short8 vf = *(const short8*)&lds[BV_OFF + (n * 16 + lo) * 264 + kv0 + hi * 8];
                acc_o[n] = __builtin_amdgcn_mfma_f32_16x16x32_bf16(vf, pf, acc_o[n], 0, 0, 0);
            }
            __builtin_amdgcn_s_setprio(0);
        }
        const float inv = 1.0f / Lr;
        float* op = out + ((size_t)(b * 256 + q_lane)) * HS_;
        #pragma unroll
        for (int n = 0; n < 4; ++n)
            #pragma unroll
            for (int r = 0; r < 4; ++r)
                op[n * 16 + hi * 4 + r] = acc_o[n][r] * inv;
    }
}

// ---------- launch ----------
extern "C" void kernel_launch(void* const* d_in, const int* in_sizes, int n_in,
                              void* d_out, int out_size, void* d_ws, size_t ws_size,
                              hipStream_t stream) {
    const float* X  = (const float*)d_in[0];
    const float* Wq = (const float*)d_in[1];
    const float* Wk = (const float*)d_in[2];
    const float* Wv = (const float*)d_in[3];
    float* out = (float*)d_out;

    unsigned short* Wfrag = (unsigned short*)d_ws;          // 144 KB
    unsigned short* Qg    = Wfrag + (size_t)9216 * 8;       // 8 MB each
    unsigned short* Kg    = Qg + (size_t)BT_ * HS_;
    unsigned short* Vtg   = Kg + (size_t)BT_ * HS_;

    prep_wfrag<<<36, 256, 0, stream>>>(Wq, Wk, Wv, Wfrag);
    qkv_a<<<BT_ / 64, 256, 0, stream>>>(X, Wfrag, Qg, Kg, Vtg);
    attn_b<<<B_, 1024, 0, stream>>>(Qg, Kg, Vtg, out);
}

// Round 10
// 36.119 us; speedup vs baseline: 1.1903x; 1.1903x over previous
//
#include <hip/hip_runtime.h>
#include <hip/hip_bf16.h>

#define B_  256
#define T_  256
#define C_  384
#define HS_ 64
#define BT_ (B_*T_)

typedef __attribute__((ext_vector_type(8))) short short8;
typedef __attribute__((ext_vector_type(4))) float f32x4;

// ---------- helpers ----------
__device__ __forceinline__ unsigned short f2bf(float f) {
    unsigned u = __float_as_uint(f);
    u += 0x7FFFu + ((u >> 16) & 1u);   // round-to-nearest-even
    return (unsigned short)(u >> 16);
}

// ---------- kernel 0: W -> MFMA-fragment-ordered bf16 ----------
// Wfrag[s][wn][f][lane] (short8): element col n = wn*48+f*16+(lane&15),
// k = s*32+(lane>>4)*8+j.  Q columns pre-scaled by 384^-0.5.
__global__ __launch_bounds__(256) void prep_wfrag(
    const float* __restrict__ Wq, const float* __restrict__ Wk,
    const float* __restrict__ Wv, unsigned short* __restrict__ Wfrag)
{
    const int tid  = blockIdx.x * 256 + threadIdx.x;   // 9216 threads
    const int lane = tid & 63;
    const int q    = tid >> 6;
    const int f    = q % 3;
    const int q2   = q / 3;
    const int wn   = q2 & 3;
    const int s    = q2 >> 2;

    const int n     = wn * 48 + f * 16 + (lane & 15);
    const int kbase = s * 32 + (lane >> 4) * 8;
    const float* src = (n < 64) ? Wq : (n < 128) ? Wk : Wv;
    const int c      = n & 63;
    const float scale = (n < 64) ? 0.05103103630798288f : 1.0f;

    short8 out;
    #pragma unroll
    for (int j = 0; j < 8; ++j)
        out[j] = (short)f2bf(src[(size_t)(kbase + j) * HS_ + c] * scale);
    *(short8*)&Wfrag[(size_t)tid * 8] = out;
}

// ---------- fused kernel: QKV projection + causal flash attention ----------
// One block per batch, 1024 thr = 16 waves (4 waves/SIMD).
// GEMM: M=256 x N=192 x K=384; wave (wm,wn) owns rows wm*64..+64, cols wn*48..+48.
// X staging depth-2 pipelined. Attention (swapped-MFMA): QK^T = mfma(K,Q) ->
// lane holds P row q=lo; in-lane softmax + defer-max (T13); P redistributed to
// the PV B-fragment IN REGISTERS via cvt_pk + permlane swaps (T12) -- no P LDS.
// PV = mfma(V,P) -> O^T (lane-local rescale).
// LDS map (u16 units):
//   Qs  [256][72]  @ 0       (18432)
//   Ks  [256][72]  @ 18432   (18432)
//   Vts [64][264]  @ 36864   (16896)   V transposed: [h][tok]
//   Xs  [2][256][40] @ 53760 (20480)   GEMM staging (dead in phase 2)
// total 74240 u16 = 148480 B
#define LQ_OFF 0
#define LK_OFF 18432
#define LV_OFF 36864
#define LX_OFF 53760

__global__ __launch_bounds__(1024, 4) void head_fused(
    const float* __restrict__ X, const unsigned short* __restrict__ Wfrag,
    float* __restrict__ out)
{
    __shared__ unsigned short lds[74240];
    const int t    = threadIdx.x;
    const int w    = t >> 6;        // 0..15
    const int lane = t & 63;
    const int lo   = lane & 15;
    const int hi   = lane >> 4;
    const int b    = blockIdx.x;
    const int wm   = w >> 2, wn = w & 3;

    const float* Xb = X + (size_t)b * T_ * C_;
    const short8* Wf = (const short8*)Wfrag;

    // ================= phase 1: QKV GEMM =================
    const int srow  = t >> 2;       // 0..255
    const int squad = t & 3;        // 8-float chunk of the 32-k slice

    auto stage_load = [&](int k0, float4* g) {
        const float* p = Xb + (size_t)srow * C_ + k0 + squad * 8;
        g[0] = *(const float4*)(p);
        g[1] = *(const float4*)(p + 4);
    };
    auto stage_write = [&](int buf, const float4* g) {
        short8 p;
        p[0] = (short)f2bf(g[0].x); p[1] = (short)f2bf(g[0].y);
        p[2] = (short)f2bf(g[0].z); p[3] = (short)f2bf(g[0].w);
        p[4] = (short)f2bf(g[1].x); p[5] = (short)f2bf(g[1].y);
        p[6] = (short)f2bf(g[1].z); p[7] = (short)f2bf(g[1].w);
        *(short8*)&lds[LX_OFF + buf * 10240 + srow * 40 + squad * 8] = p;
    };
    auto load_w = [&](int s, short8* wf) {      // coalesced fragment loads
        const short8* base = Wf + ((size_t)(s * 4 + wn) * 3) * 64 + lane;
        #pragma unroll
        for (int f = 0; f < 3; ++f)
            wf[f] = base[f * 64];
    };

    float4 gx[2][2];                 // depth-2 X pipeline
    short8 wfr[2][3];
    stage_load(0, gx[0]);
    load_w(0, wfr[0]);
    stage_load(32, gx[1]);
    stage_write(0, gx[0]);
    __syncthreads();

    f32x4 acc[4][3];
    #pragma unroll
    for (int m = 0; m < 4; ++m)
        #pragma unroll
        for (int f = 0; f < 3; ++f)
            acc[m][f] = (f32x4){0.f, 0.f, 0.f, 0.f};

    #pragma unroll 2
    for (int s = 0; s < 12; ++s) {
        const int cur = s & 1;
        if (s < 10) stage_load((s + 2) * 32, gx[cur]);     // issue 2 ahead
        if (s < 11) load_w(s + 1, wfr[cur ^ 1]);           // W 1 ahead
        if (s < 11) stage_write(cur ^ 1, gx[cur ^ 1]);     // write s+1 (arrived)

        short8 af[4];                               // A-frag: row=lo, k=hi*8+j
        #pragma unroll
        for (int m = 0; m < 4; ++m)
            af[m] = *(const short8*)&lds[LX_OFF + cur * 10240 + (wm * 64 + m * 16 + lo) * 40 + hi * 8];
        #pragma unroll
        for (int m = 0; m < 4; ++m)
            #pragma unroll
            for (int f = 0; f < 3; ++f)
                acc[m][f] = __builtin_amdgcn_mfma_f32_16x16x32_bf16(af[m], wfr[cur][f], acc[m][f], 0, 0, 0);
        __syncthreads();
    }

    // epilogue: D col = wn*48+f*16+lo, row = wm*64+m*16+hi*4+r  -> LDS Q/K/Vt
    #pragma unroll
    for (int m = 0; m < 4; ++m) {
        const int rowb = wm * 64 + m * 16 + hi * 4;
        #pragma unroll
        for (int f = 0; f < 3; ++f) {
            const int base = wn * 48 + f * 16;      // frag fully inside one of Q/K/V
            if (base < 64) {
                #pragma unroll
                for (int r = 0; r < 4; ++r)
                    lds[LQ_OFF + (rowb + r) * 72 + base + lo] = f2bf(acc[m][f][r]);
            } else if (base < 128) {
                #pragma unroll
                for (int r = 0; r < 4; ++r)
                    lds[LK_OFF + (rowb + r) * 72 + (base - 64) + lo] = f2bf(acc[m][f][r]);
            } else {
                ushort4 pk = { f2bf(acc[m][f][0]), f2bf(acc[m][f][1]),
                               f2bf(acc[m][f][2]), f2bf(acc[m][f][3]) };
                *(ushort4*)&lds[LV_OFF + (base - 128 + lo) * 264 + rowb] = pk;
            }
        }
    }
    __syncthreads();

    // ======== phase 2: causal flash attention (swapped MFMA, reg-only P) ========
    // SIMD-balanced tile assignment: SIMD g gets {g, 15-g, 4+g, 11-g} = 18 steps
    const int sg  = w & 3, pos = w >> 2;
    const int tq  = (pos == 0) ? sg : (pos == 1) ? 15 - sg : (pos == 2) ? 4 + sg : 11 - sg;

    {
        const int q_lane = tq * 16 + lo;            // this lane's q row
        // Q as B-frag: col=q=lo, k=hi*8+j (+32)
        short8 qf0 = *(const short8*)&lds[LQ_OFF + q_lane * 72 + hi * 8];
        short8 qf1 = *(const short8*)&lds[LQ_OFF + q_lane * 72 + hi * 8 + 32];

        f32x4 acc_o[4];                             // O^T: acc_o[n][r] = O[h=n*16+hi*4+r][q=lo]
        #pragma unroll
        for (int n = 0; n < 4; ++n) acc_o[n] = (f32x4){0.f, 0.f, 0.f, 0.f};
        float Mr = -1e30f, Lr = 0.f;

        const int nsteps = (tq >> 1) + 1;
        for (int s = 0; s < nsteps; ++s) {
            const int kv0 = s * 32;
            // QK^T swapped: D[row=kv][col=q]; lane holds P[kv=kv0+n*16+hi*4+r][q=lo]
            f32x4 sb[2];
            sb[0] = (f32x4){0.f, 0.f, 0.f, 0.f};
            sb[1] = (f32x4){0.f, 0.f, 0.f, 0.f};
            __builtin_amdgcn_s_setprio(1);
            #pragma unroll
            for (int n = 0; n < 2; ++n) {
                const unsigned short* kb = &lds[LK_OFF + (kv0 + n * 16 + lo) * 72 + hi * 8];
                short8 kf0 = *(const short8*)kb;
                short8 kf1 = *(const short8*)(kb + 32);
                sb[n] = __builtin_amdgcn_mfma_f32_16x16x32_bf16(kf0, qf0, sb[n], 0, 0, 0);
                sb[n] = __builtin_amdgcn_mfma_f32_16x16x32_bf16(kf1, qf1, sb[n], 0, 0, 0);
            }
            __builtin_amdgcn_s_setprio(0);
            if (s == nsteps - 1) {                  // causal: kv = kv0+n*16+hi*4+r
                #pragma unroll
                for (int n = 0; n < 2; ++n)
                    #pragma unroll
                    for (int r = 0; r < 4; ++r)
                        if (kv0 + n * 16 + hi * 4 + r > q_lane) sb[n][r] = -1e30f;
            }
            // in-lane softmax for row q=lo
            float pmax = fmaxf(fmaxf(fmaxf(sb[0][0], sb[0][1]), fmaxf(sb[0][2], sb[0][3])),
                               fmaxf(fmaxf(sb[1][0], sb[1][1]), fmaxf(sb[1][2], sb[1][3])));
            pmax = fmaxf(pmax, __shfl_xor(pmax, 16));
            pmax = fmaxf(pmax, __shfl_xor(pmax, 32));
            float Mn;
            if (__all(pmax - Mr <= 8.0f)) {         // T13 defer-max: skip rescale
                Mn = Mr;
            } else {
                Mn = fmaxf(Mr, pmax);
                const float fr = __expf(Mr - Mn);
                Mr = Mn;
                Lr *= fr;
                #pragma unroll
                for (int n = 0; n < 4; ++n) {
                    acc_o[n][0] *= fr; acc_o[n][1] *= fr;
                    acc_o[n][2] *= fr; acc_o[n][3] *= fr;
                }
            }
            float p0 = __expf(sb[0][0] - Mn), p1 = __expf(sb[0][1] - Mn);
            float p2 = __expf(sb[0][2] - Mn), p3 = __expf(sb[0][3] - Mn);
            float p4 = __expf(sb[1][0] - Mn), p5 = __expf(sb[1][1] - Mn);
            float p6 = __expf(sb[1][2] - Mn), p7 = __expf(sb[1][3] - Mn);
            float ls = ((p0 + p1) + (p2 + p3)) + ((p4 + p5) + (p6 + p7));
            ls += __shfl_xor(ls, 16);
            ls += __shfl_xor(ls, 32);
            Lr += ls;
            // ---- T12: P -> PV B-frag entirely in registers ----
            // lane g=hi holds bf16 pairs A=pi(2g) B=pi(2g+1) C=pi(8+2g) D=pi(8+2g+1);
            // target lane g'=hi needs T_m = pi(4g'+m).
            // {T0,T2} = pl16swap(pl32swap(A,C)); {T1,T3} = pl16swap(pl32swap(B,D)).
            unsigned Ap, Bp, Cp, Dp;
            asm("v_cvt_pk_bf16_f32 %0, %1, %2" : "=v"(Ap) : "v"(p0), "v"(p1));
            asm("v_cvt_pk_bf16_f32 %0, %1, %2" : "=v"(Bp) : "v"(p2), "v"(p3));
            asm("v_cvt_pk_bf16_f32 %0, %1, %2" : "=v"(Cp) : "v"(p4), "v"(p5));
            asm("v_cvt_pk_bf16_f32 %0, %1, %2" : "=v"(Dp) : "v"(p6), "v"(p7));
            asm("v_permlane32_swap_b32 %0, %1" : "+v"(Ap), "+v"(Cp));
            asm("v_permlane16_swap_b32 %0, %1" : "+v"(Ap), "+v"(Cp));
            asm("v_permlane32_swap_b32 %0, %1" : "+v"(Bp), "+v"(Dp));
            asm("v_permlane16_swap_b32 %0, %1" : "+v"(Bp), "+v"(Dp));
            uint4 pfu = { Ap, Bp, Cp, Dp };         // T0,T1,T2,T3 (k ascending)
            short8 pf = *(short8*)&pfu;
            // PV swapped: A = Vt rows (h), B = P (col=q); D[row=h][col=q]
            __builtin_amdgcn_s_setprio(1);
            #pragma unroll
            for (int n = 0; n < 4; ++n) {
                short8 vf = *(const short8*)&lds[LV_OFF + (n * 16 + lo) * 264 + kv0 + hi * 8];
                acc_o[n] = __builtin_amdgcn_mfma_f32_16x16x32_bf16(vf, pf, acc_o[n], 0, 0, 0);
            }
            __builtin_amdgcn_s_setprio(0);
        }
        // epilogue: out[q=q_lane][h=n*16+hi*4+r] = acc_o[n][r]/Lr
        const float inv = 1.0f / Lr;
        float* op = out + ((size_t)(b * 256 + q_lane)) * HS_;
        #pragma unroll
        for (int n = 0; n < 4; ++n)
            #pragma unroll
            for (int r = 0; r < 4; ++r)
                op[n * 16 + hi * 4 + r] = acc_o[n][r] * inv;
    }
}

// ---------- launch ----------
extern "C" void kernel_launch(void* const* d_in, const int* in_sizes, int n_in,
                              void* d_out, int out_size, void* d_ws, size_t ws_size,
                              hipStream_t stream) {
    const float* X  = (const float*)d_in[0];
    const float* Wq = (const float*)d_in[1];
    const float* Wk = (const float*)d_in[2];
    const float* Wv = (const float*)d_in[3];
    float* out = (float*)d_out;

    unsigned short* Wfrag = (unsigned short*)d_ws;   // 12*4*3*64*8 u16 = 144 KB

    prep_wfrag<<<36, 256, 0, stream>>>(Wq, Wk, Wv, Wfrag);
    head_fused<<<B_, 1024, 0, stream>>>(X, Wfrag, out);
}